// Round 1
// baseline (91.344 us; speedup 1.0000x reference)
//
#include <hip/hip_runtime.h>

#define SEQ 256
#define LOG2E 1.44269504088896340736f

__global__ __launch_bounds__(SEQ) void pico_transformer_kernel(
    const float* __restrict__ x,      // [B,S]
    const float* __restrict__ emb_w,  // [4,1]
    const float* __restrict__ emb_b,  // [4]
    const float* __restrict__ q_w,    // [4,4]
    const float* __restrict__ q_b,    // [4]
    const float* __restrict__ k_w,    // [4,4]
    const float* __restrict__ k_b,    // [4]
    const float* __restrict__ v_w,    // [4,4]
    const float* __restrict__ v_b,    // [4]
    const float* __restrict__ f1_w,   // [8,4]
    const float* __restrict__ f1_b,   // [8]
    const float* __restrict__ f2_w,   // [1,8]
    const float* __restrict__ f2_b,   // [1]
    float* __restrict__ out)          // [B]
{
    __shared__ float xs[SEQ];
    __shared__ float consts[27];   // [0]=c1*log2e [1]=c3*log2e [2..9]=u [10..17]=w [18..25]=f2w [26]=f2b
    __shared__ float red_mx[4], red_mn[4], red_sum[4];

    const int tid = threadIdx.x;
    const int b   = blockIdx.x;

    // Stage this batch row of x into LDS (coalesced global read).
    float xv = x[b * SEQ + tid];
    xs[tid] = xv;

    // Thread 0 folds the tiny weight stack into 27 scalars (all weight
    // reads hit L2/L3 — every block does this redundantly, ~200 flops).
    if (tid == 0) {
        float we[4], be[4], Aq[4], Bq[4], Ak[4], Av[4], Bv[4];
        #pragma unroll
        for (int d = 0; d < 4; ++d) { we[d] = emb_w[d]; be[d] = emb_b[d]; }
        #pragma unroll
        for (int e = 0; e < 4; ++e) {
            float aq = 0.f, bq = 0.f, ak = 0.f, av = 0.f, bv = 0.f;
            #pragma unroll
            for (int d = 0; d < 4; ++d) {
                aq += q_w[e*4+d] * we[d];
                bq += q_w[e*4+d] * be[d];
                ak += k_w[e*4+d] * we[d];
                av += v_w[e*4+d] * we[d];
                bv += v_w[e*4+d] * be[d];
            }
            Aq[e] = aq; Bq[e] = bq + q_b[e]; Ak[e] = ak;
            Av[e] = av; Bv[e] = bv + v_b[e];
        }
        float c1 = 0.f, c3 = 0.f;
        #pragma unroll
        for (int d = 0; d < 4; ++d) { c1 += Aq[d]*Ak[d]; c3 += Bq[d]*Ak[d]; }
        consts[0] = 0.5f * c1 * LOG2E;   // temperature slope (log2 domain)
        consts[1] = 0.5f * c3 * LOG2E;   // temperature offset
        #pragma unroll
        for (int j = 0; j < 8; ++j) {
            float u = 0.f, w = 0.f;
            #pragma unroll
            for (int d = 0; d < 4; ++d) {
                u += f1_w[j*4+d] * Av[d];
                w += f1_w[j*4+d] * Bv[d];
            }
            consts[2 + j]  = u;
            consts[10 + j] = w + f1_b[j];
            consts[18 + j] = f2_w[j];
        }
        consts[26] = f2_b[0];
    }

    // Block max/min of x row (for exact softmax max-subtraction:
    // max_j t*x_j = t>=0 ? t*xmax : t*xmin). Wave64 shuffle then LDS.
    float mx = xv, mn = xv;
    #pragma unroll
    for (int off = 32; off > 0; off >>= 1) {
        mx = fmaxf(mx, __shfl_down(mx, off, 64));
        mn = fminf(mn, __shfl_down(mn, off, 64));
    }
    if ((tid & 63) == 0) { red_mx[tid >> 6] = mx; red_mn[tid >> 6] = mn; }

    __syncthreads();  // covers xs, consts, red_mx/red_mn

    const float XMAX = fmaxf(fmaxf(red_mx[0], red_mx[1]), fmaxf(red_mx[2], red_mx[3]));
    const float XMIN = fminf(fminf(red_mn[0], red_mn[1]), fminf(red_mn[2], red_mn[3]));

    // Per-query temperature (log2 domain) and its row max.
    const float t2 = consts[0] * xv + consts[1];
    const float m2 = (t2 >= 0.f) ? t2 * XMAX : t2 * XMIN;

    // g(t) = sum_j x_j 2^(t2*x_j - m2) / sum_j 2^(t2*x_j - m2)
    // All lanes read the same xs element per iter -> LDS broadcast, no conflicts.
    float num = 0.f, den = 0.f;
    const float4* xs4 = (const float4*)xs;
    #pragma unroll 4
    for (int j4 = 0; j4 < SEQ / 4; ++j4) {
        float4 xq = xs4[j4];
        float e0 = __builtin_amdgcn_exp2f(t2 * xq.x - m2);
        float e1 = __builtin_amdgcn_exp2f(t2 * xq.y - m2);
        float e2 = __builtin_amdgcn_exp2f(t2 * xq.z - m2);
        float e3 = __builtin_amdgcn_exp2f(t2 * xq.w - m2);
        num += xq.x * e0 + xq.y * e1 + xq.z * e2 + xq.w * e3;
        den += (e0 + e1) + (e2 + e3);
    }
    float g = num / den;

    // Mean over the 256 queries.
    #pragma unroll
    for (int off = 32; off > 0; off >>= 1) g += __shfl_down(g, off, 64);
    if ((tid & 63) == 0) red_sum[tid >> 6] = g;
    __syncthreads();

    if (tid == 0) {
        float G = (red_sum[0] + red_sum[1] + red_sum[2] + red_sum[3]) * (1.0f / SEQ);
        float acc = consts[26];
        #pragma unroll
        for (int j = 0; j < 8; ++j) {
            float hv = fmaxf(G * consts[2 + j] + consts[10 + j], 0.f);
            acc += hv * consts[18 + j];
        }
        out[b] = acc;
    }
}

extern "C" void kernel_launch(void* const* d_in, const int* in_sizes, int n_in,
                              void* d_out, int out_size, void* d_ws, size_t ws_size,
                              hipStream_t stream) {
    const float* x     = (const float*)d_in[0];
    const float* emb_w = (const float*)d_in[1];
    const float* emb_b = (const float*)d_in[2];
    const float* q_w   = (const float*)d_in[3];
    const float* q_b   = (const float*)d_in[4];
    const float* k_w   = (const float*)d_in[5];
    const float* k_b   = (const float*)d_in[6];
    const float* v_w   = (const float*)d_in[7];
    const float* v_b   = (const float*)d_in[8];
    const float* f1_w  = (const float*)d_in[9];
    const float* f1_b  = (const float*)d_in[10];
    const float* f2_w  = (const float*)d_in[11];
    const float* f2_b  = (const float*)d_in[12];
    float* out = (float*)d_out;

    const int B = in_sizes[0] / SEQ;   // 1024
    pico_transformer_kernel<<<B, SEQ, 0, stream>>>(
        x, emb_w, emb_b, q_w, q_b, k_w, k_b, v_w, v_b,
        f1_w, f1_b, f2_w, f2_b, out);
}